// Round 10
// baseline (284.171 us; speedup 1.0000x reference)
//
#include <hip/hip_runtime.h>
#include <math.h>

// Problem constants
#define NROWS 8192
#define KCODES 8192
#define DDIM 1024
#define ZQ_ELEMS 8388608  // 8*1024*32*32

typedef int i4 __attribute__((ext_vector_type(4)));   // i8 MFMA operands / i32 acc

// ===================== T0 ws layout (i8 + candidates; zT lives in d_out) =====================
#define W0_QZ8     0u
#define W0_QE8     8388608u
#define W0_SZ      16777216u
#define W0_SE      16809984u
#define W0_CAND    16842752u   // u16 8192*128
#define W0_CVAL    18939904u   // f32 8192*128
#define W0_CCNT    23134208u
#define W0_COUNTS  23166976u
#define W0_ZNORM   23199744u
#define W0_ROWMIN  23232512u
#define W0_NEED    23265280u
// ===================== T1 ws layout (i8 buffers in d_out) =====================
#define W1_CAND    0u
#define W1_CVAL    2097152u
#define W1_CCNT    6291456u
#define W1_COUNTS  6324224u
#define W1_ZNORM   6356992u
#define W1_ROWMIN  6389760u
#define W1_NEED    6422528u
// ===================== T3 ws layout =====================
#define W3_CAND    0u
#define W3_CCNT    2097152u
#define W3_COUNTS  2129920u
#define W3_ZNORM   2162688u
#define W3_ROWMIN  2195456u
#define W3_NEED    2228224u

#define CAP 128
#define MARGIN  7.5e-4f  // stage1 collection margin (>=9 sigma of i8 s1 error + bucket)
#define MARGIN2 6e-4f    // stage2 filter margin (~8.7 sigma + bucket)

typedef __attribute__((address_space(3))) unsigned int lds_u32;
typedef __attribute__((address_space(1))) const unsigned int glb_u32;
static __device__ __forceinline__ void glds16(const void* g, void* l) {
    __builtin_amdgcn_global_load_lds((glb_u32*)g, (lds_u32*)l, 16, 0, 0);
}

// ---------------- fused prep: z single-pass (norm+max+zT+quantize from regs) + e quant ----------------
// blocks [0,512): z strip (b, 16 hw); blocks [512,4608): 2 emb rows each.
// z part: 64d x 16hw dbuf transpose tile, values held in 16 float4 regs;
// norm/max via 16-lane butterfly (all lanes get result -> no LDS broadcast);
// quantize straight from registers -> NO second pass at all.
__global__ __launch_bounds__(256) void prep_kernel(const float* __restrict__ z,
                                                   const float* __restrict__ emb,
                                                   char* __restrict__ qz8,
                                                   char* __restrict__ qe8,
                                                   float* __restrict__ sz,
                                                   float* __restrict__ se,
                                                   float* __restrict__ zT,
                                                   float* __restrict__ zn,
                                                   unsigned int* __restrict__ ccnt,
                                                   float* __restrict__ counts,
                                                   int* __restrict__ rowming,
                                                   float* __restrict__ outbuf) {
    int blk = blockIdx.x;
    int t = threadIdx.x;
    if (blk >= 512) {
        // ---- emb rows: per-row max -> scale -> int8 ----
        __shared__ float wm[4];
        int k0 = (blk - 512) * 2;
        int half = t >> 7;
        int li = t & 127;
        int row = k0 + half;
        const float* er = emb + (size_t)row * 1024 + li * 8;
        float4 v0 = *(const float4*)er;
        float4 v1 = *(const float4*)(er + 4);
        float lm = fmaxf(fmaxf(fmaxf(fabsf(v0.x), fabsf(v0.y)), fmaxf(fabsf(v0.z), fabsf(v0.w))),
                         fmaxf(fmaxf(fabsf(v1.x), fabsf(v1.y)), fmaxf(fabsf(v1.z), fabsf(v1.w))));
#pragma unroll
        for (int off = 32; off; off >>= 1) lm = fmaxf(lm, __shfl_down(lm, off, 64));
        int w = t >> 6;
        if ((t & 63) == 0) wm[w] = lm;
        __syncthreads();
        float rmax = fmaxf(wm[half * 2], wm[half * 2 + 1]);
        float inv = rmax > 0.f ? 127.f / rmax : 0.f;
        int q0 = (int)rintf(v0.x * inv), q1 = (int)rintf(v0.y * inv);
        int q2 = (int)rintf(v0.z * inv), q3 = (int)rintf(v0.w * inv);
        int q4 = (int)rintf(v1.x * inv), q5 = (int)rintf(v1.y * inv);
        int q6 = (int)rintf(v1.z * inv), q7 = (int)rintf(v1.w * inv);
        uint2 o;
        o.x = (q0 & 255) | ((q1 & 255) << 8) | ((q2 & 255) << 16) | ((unsigned)(q3 & 255) << 24);
        o.y = (q4 & 255) | ((q5 & 255) << 8) | ((q6 & 255) << 16) | ((unsigned)(q7 & 255) << 24);
        *(uint2*)(qe8 + (size_t)row * 1024 + li * 8) = o;
        if (li == 0) se[row] = rmax * (1.f / 127.f);
        return;
    }
    // init slices (blocks 0..255 cover 8192)
    if (blk < 256 && t < 32) {
        int i = blk * 32 + t;
        ccnt[i] = 0u;
        counts[i] = 0.f;
        rowming[i] = 0x7f7f7f7f;
    }
    if (blk == 0 && t == 32) outbuf[ZQ_ELEMS] = 0.f;

    __shared__ float T[2][64 * 17];
    int b = blk >> 6;
    int hw0 = (blk & 63) * 16;
    int dsub = t >> 2, hseg = (t & 3) * 4;   // load role: 64 d x 16 hw
    int hsub = t >> 4, ddg = (t & 15) * 4;   // emit role: 16 hw x 16 d-groups
    double acc = 0.0;
    float lmax = 0.f;
    float4 tv[16];
    int p = 0;
#pragma unroll
    for (int dt = 0; dt < 16; ++dt) {
        int d0 = dt * 64;
        float4 v = *(const float4*)(z + (size_t)b * 1048576 + (size_t)(d0 + dsub) * 1024 + hw0 + hseg);
        float* Tp = T[p];
        Tp[dsub * 17 + hseg + 0] = v.x;
        Tp[dsub * 17 + hseg + 1] = v.y;
        Tp[dsub * 17 + hseg + 2] = v.z;
        Tp[dsub * 17 + hseg + 3] = v.w;
        __syncthreads();
        float t0 = Tp[(ddg + 0) * 17 + hsub];
        float t1 = Tp[(ddg + 1) * 17 + hsub];
        float t2 = Tp[(ddg + 2) * 17 + hsub];
        float t3 = Tp[(ddg + 3) * 17 + hsub];
        tv[dt].x = t0; tv[dt].y = t1; tv[dt].z = t2; tv[dt].w = t3;
        if (zT) {
            float4 o4; o4.x = t0; o4.y = t1; o4.z = t2; o4.w = t3;
            *(float4*)(zT + ((size_t)(b * 1024 + hw0 + hsub) << 10) + d0 + ddg) = o4;
        }
        acc += (double)t0 * t0 + (double)t1 * t1 + (double)t2 * t2 + (double)t3 * t3;
        lmax = fmaxf(lmax, fmaxf(fmaxf(fabsf(t0), fabsf(t1)), fmaxf(fabsf(t2), fabsf(t3))));
        p ^= 1;
    }
#pragma unroll
    for (int m = 8; m; m >>= 1) {
        acc += __shfl_xor(acc, m, 16);
        lmax = fmaxf(lmax, __shfl_xor(lmax, m, 16));
    }
    if ((t & 15) == 0) {
        zn[b * 1024 + hw0 + hsub] = (float)acc;
        sz[b * 1024 + hw0 + hsub] = lmax * (1.f / 127.f);
    }
    // quantize straight from registers (same inv bits as the 2-pass version)
    float inv = lmax > 0.f ? 127.f / lmax : 0.f;
    int* qo = (int*)(qz8 + ((size_t)(b * 1024 + hw0 + hsub) << 10) + ddg);
#pragma unroll
    for (int dt = 0; dt < 16; ++dt) {
        int q0 = (int)rintf(tv[dt].x * inv), q1 = (int)rintf(tv[dt].y * inv);
        int q2 = (int)rintf(tv[dt].z * inv), q3 = (int)rintf(tv[dt].w * inv);
        qo[dt * 16] = (q0 & 255) | ((q1 & 255) << 8) | ((q2 & 255) << 16) | ((unsigned)(q3 & 255) << 24);
    }
}

// ---------------- |z_n|^2 standalone (fp32 fallback path only) ----------------
__global__ __launch_bounds__(256) void znorm_kernel(const float* __restrict__ z,
                                                    float* __restrict__ zn) {
    int b = blockIdx.x >> 2;
    int hw = (blockIdx.x & 3) * 256 + threadIdx.x;
    const float* base = z + (size_t)b * 1048576 + hw;
    double s = 0.0;
#pragma unroll 16
    for (int d = 0; d < DDIM; ++d) {
        float v = base[(size_t)d * 1024];
        s += (double)v * (double)v;
    }
    zn[b * 1024 + hw] = (float)s;
}

// ---------------- stage 1: i8 MFMA GEMM + candidate collect ----------------
// grid (64 x 64), 256 thr (4 waves 2x2), tile 128x128, BK=128 i8, 8 segments.
// CONFIRMED LOCAL OPTIMUM schedule (105us); linear dispatch already XCD-optimal
// (R8: remapping regressed, FETCH 43.5->232MB). This round: prefix-min share
// made fire-and-forget -- plain load (latency-hidden) + no-return atomicMin.
// SAFE under staleness: the block computing a row's true min has mine==s1_min,
// so rm >= s1_min+MARGIN regardless of gold; staleness only loosens.
__global__ __launch_bounds__(256, 4) void stage1_kernel(const char* __restrict__ qz,
                                                        const char* __restrict__ qe,
                                                        const float* __restrict__ sz,
                                                        const float* __restrict__ se,
                                                        unsigned short* __restrict__ cand,
                                                        float* __restrict__ cval,
                                                        unsigned int* __restrict__ ccnt,
                                                        int* __restrict__ rowming) {
    __shared__ char As[128 * 128];   // [row][8 chunks of 16 i8], chunk ^= row&7
    __shared__ char Bs[128 * 128];
    __shared__ int rowminS[128];
    __shared__ float szS[128], seS[128];

    int t = threadIdx.x;
    int w = t >> 6, lane = t & 63;
    int q = lane >> 4, l15 = lane & 15;
    int wr = (w >> 1) * 64, wc = (w & 1) * 64;
    int n0 = blockIdx.x * 128;
    int k0 = blockIdx.y * 128;
    if (t < 128) {
        rowminS[t] = 0x7f7f7f7f;
        szS[t] = sz[n0 + t];
        seS[t] = se[k0 + t];
    }

    const char* gA[4];
    const char* gB[4];
    {
        int rsub = lane >> 3;
        int clog = (lane & 7) ^ (rsub & 7);
#pragma unroll
        for (int c = 0; c < 4; ++c) {
            int cc = w * 4 + c;
            int r = cc * 8 + rsub;
            gA[c] = qz + ((size_t)(n0 + r) << 10) + clog * 16;
            gB[c] = qe + ((size_t)(k0 + r) << 10) + clog * 16;
        }
    }
    int Aoff[4][2], Boff[4][2];
#pragma unroll
    for (int rf = 0; rf < 4; ++rf) {
#pragma unroll
        for (int ks = 0; ks < 2; ++ks) {
            int r = wr + rf * 16 + l15;
            Aoff[rf][ks] = r * 128 + (((ks * 4 + q) ^ (r & 7)) * 16);
            int rb = wc + rf * 16 + l15;
            Boff[rf][ks] = rb * 128 + (((ks * 4 + q) ^ (rb & 7)) * 16);
        }
    }

    i4 acc[4][4];
    const i4 z4 = {0, 0, 0, 0};
#pragma unroll
    for (int rf = 0; rf < 4; ++rf)
#pragma unroll
        for (int cf = 0; cf < 4; ++cf) acc[rf][cf] = z4;

    for (int s = 0; s < 8; ++s) {
        __syncthreads();
#pragma unroll
        for (int c = 0; c < 4; ++c) {
            int cc = w * 4 + c;
            glds16(gA[c], As + cc * 1024);
            glds16(gB[c], Bs + cc * 1024);
            gA[c] += 128;
            gB[c] += 128;
        }
        __syncthreads();
#pragma unroll
        for (int ks = 0; ks < 2; ++ks) {
            i4 af[4], bf[4];
#pragma unroll
            for (int rf = 0; rf < 4; ++rf) af[rf] = *(const i4*)(As + Aoff[rf][ks]);
#pragma unroll
            for (int cf = 0; cf < 4; ++cf) bf[cf] = *(const i4*)(Bs + Boff[cf][ks]);
#pragma unroll
            for (int rf = 0; rf < 4; ++rf)
#pragma unroll
                for (int cf = 0; cf < 4; ++cf)
                    acc[rf][cf] = __builtin_amdgcn_mfma_i32_16x16x64_i8(af[rf], bf[cf], acc[rf][cf], 0, 0, 0);
        }
    }

    // plain (latency-hideable) read of the shared prefix-min; consumed ~200 ops later
    int goldv = 0x7f7f7f7f;
    if (t < 128) goldv = rowming[n0 + t];

    // ---- epilogue: s1 = 16 - 2*idot*sz*se (positive -> int-ordered min) ----
#pragma unroll
    for (int rf = 0; rf < 4; ++rf) {
#pragma unroll
        for (int reg = 0; reg < 4; ++reg) {
            int r = wr + rf * 16 + q * 4 + reg;
            float zs = szS[r];
            float m4 = INFINITY;
#pragma unroll
            for (int cf = 0; cf < 4; ++cf) {
                float s1 = 16.0f - 2.0f * (float)acc[rf][cf][reg] * (zs * seS[wc + cf * 16 + l15]);
                m4 = fminf(m4, s1);
            }
            m4 = fminf(m4, __shfl_xor(m4, 1, 16));
            m4 = fminf(m4, __shfl_xor(m4, 2, 16));
            m4 = fminf(m4, __shfl_xor(m4, 4, 16));
            m4 = fminf(m4, __shfl_xor(m4, 8, 16));
            if (l15 == 0) atomicMin(&rowminS[r], __float_as_int(m4));
        }
    }
    __syncthreads();
    if (t < 128) {
        int mine = rowminS[t];
        atomicMin(&rowming[n0 + t], mine);          // fire-and-forget publish
        rowminS[t] = goldv < mine ? goldv : mine;   // combine with (stale-ok) read
    }
    __syncthreads();
#pragma unroll
    for (int rf = 0; rf < 4; ++rf) {
#pragma unroll
        for (int reg = 0; reg < 4; ++reg) {
            int r = wr + rf * 16 + q * 4 + reg;
            float zs = szS[r];
            float rm = __int_as_float(rowminS[r]) + MARGIN;
#pragma unroll
            for (int cf = 0; cf < 4; ++cf) {
                float s1 = 16.0f - 2.0f * (float)acc[rf][cf][reg] * (zs * seS[wc + cf * 16 + l15]);
                if (s1 <= rm) {
                    int kg = k0 + wc + cf * 16 + l15;
                    unsigned pos = atomicAdd(&ccnt[n0 + r], 1u);
                    if (pos < CAP) {
                        cand[(size_t)(n0 + r) * CAP + pos] = (unsigned short)kg;
                        if (cval) cval[(size_t)(n0 + r) * CAP + pos] = s1;
                    }
                }
            }
        }
    }
}

// ---------------- stage 2: 1 wave per row; ballot fast-exit, else exact rescore ----------------
__global__ __launch_bounds__(256) void stage2_kernel(const float* __restrict__ z,
                                                     const float* __restrict__ zT,
                                                     const float* __restrict__ emb,
                                                     const unsigned short* __restrict__ cand,
                                                     const float* __restrict__ cval,
                                                     const unsigned int* __restrict__ ccnt,
                                                     const float* __restrict__ zn,
                                                     float* __restrict__ counts,
                                                     float* __restrict__ outbuf) {
    int t = threadIdx.x;
    int w = t >> 6, lane = t & 63;
    int n = blockIdx.x * 4 + w;
    unsigned cnt = ccnt[n];
    float Zn = zn[n];
    float thr = INFINITY;

    if (cval && cnt <= CAP) {
        const float* cv = cval + (size_t)n * CAP;
        float v0 = (unsigned)lane < cnt ? cv[lane] : INFINITY;
        float v1 = (unsigned)(64 + lane) < cnt ? cv[64 + lane] : INFINITY;
        float m = fminf(v0, v1);
#pragma unroll
        for (int off = 32; off; off >>= 1) m = fminf(m, __shfl_xor(m, off, 64));
        thr = m + MARGIN2;
        unsigned long long m0 = __ballot(v0 <= thr);
        unsigned long long m1 = __ballot(v1 <= thr);
        if (__popcll(m0) + __popcll(m1) == 1) {
            if (lane == 0) {
                int slot = m0 ? ((int)__ffsll((unsigned long long)m0) - 1)
                              : 64 + ((int)__ffsll((unsigned long long)m1) - 1);
                int K = cand[(size_t)n * CAP + slot];
                outbuf[ZQ_ELEMS + 2 + n] = (float)K;
                atomicAdd(&counts[K], 1.0f);
            }
            return;
        }
    }
    // ambiguous (or no cval / overflow): z row -> registers, exact rescore
    float4 zreg[4];
    if (zT) {
        const float4* zr = (const float4*)(zT + ((size_t)n << 10));
#pragma unroll
        for (int i = 0; i < 4; ++i) zreg[i] = zr[lane + i * 64];
    } else {
        int b = n >> 10, hw = n & 1023;
        const float* zb = z + (size_t)b * 1048576 + hw;
#pragma unroll
        for (int i = 0; i < 4; ++i) {
            int e = (lane + i * 64) * 4;
            zreg[i].x = zb[(size_t)(e + 0) << 10];
            zreg[i].y = zb[(size_t)(e + 1) << 10];
            zreg[i].z = zb[(size_t)(e + 2) << 10];
            zreg[i].w = zb[(size_t)(e + 3) << 10];
        }
    }
    float bs = INFINITY;
    int bk = 0x7fffffff;
    if (cnt <= CAP) {
        for (unsigned c = 0; c < cnt; ++c) {
            if (cval && cval[(size_t)n * CAP + c] > thr) continue;
            int k = cand[(size_t)n * CAP + c];
            const float4* e4 = (const float4*)(emb + (size_t)k * 1024);
            double pd = 0.0;
#pragma unroll
            for (int i = 0; i < 4; ++i) {
                float4 e = e4[lane + i * 64];
                float4 zv = zreg[i];
                float p = (zv.x * e.x + zv.y * e.y) + (zv.z * e.z + zv.w * e.w);
                pd += (double)p;
            }
#pragma unroll
            for (int off = 32; off; off >>= 1) pd += __shfl_down(pd, off, 64);
            if (lane == 0) {
                float s = Zn - 2.0f * (float)pd;   // fl(Z + |e|^2) == Z (|e|^2 < half-ulp)
                if (s < bs || (s == bs && k < bk)) { bs = s; bk = k; }
            }
        }
    } else {
        for (int k = 0; k < KCODES; ++k) {
            const float4* e4 = (const float4*)(emb + (size_t)k * 1024);
            double pd = 0.0;
#pragma unroll
            for (int i = 0; i < 4; ++i) {
                float4 e = e4[lane + i * 64];
                float4 zv = zreg[i];
                float p = (zv.x * e.x + zv.y * e.y) + (zv.z * e.z + zv.w * e.w);
                pd += (double)p;
            }
#pragma unroll
            for (int off = 32; off; off >>= 1) pd += __shfl_down(pd, off, 64);
            if (lane == 0) {
                float s = Zn - 2.0f * (float)pd;
                if (s < bs || (s == bs && k < bk)) { bs = s; bk = k; }
            }
        }
    }
    if (lane == 0) {
        outbuf[ZQ_ELEMS + 2 + n] = (float)bk;
        atomicAdd(&counts[bk], 1.0f);
    }
}

// ---------------- perplexity standalone (fallback path only) ----------------
__global__ __launch_bounds__(1024) void perp_kernel(const float* __restrict__ counts,
                                                    float* __restrict__ outbuf) {
    __shared__ double sh[16];
    int tid = threadIdx.x;
    double h = 0.0;
    for (int i = tid; i < KCODES; i += 1024) {
        float c = counts[i];
        float p = c * (1.0f / 8192.0f);
        h += (double)(p * logf(p + 1e-10f));
    }
#pragma unroll
    for (int off = 32; off; off >>= 1) h += __shfl_down(h, off, 64);
    if ((tid & 63) == 0) sh[tid >> 6] = h;
    __syncthreads();
    if (tid == 0) {
        double H = 0.0;
#pragma unroll
        for (int i = 0; i < 16; ++i) H += sh[i];
        outbuf[ZQ_ELEMS + 1] = (float)exp(-H);
    }
}

// ---------------- gather + transpose + STE + loss (+ fused perplexity in block 0) ----------------
__global__ __launch_bounds__(256) void gather_kernel(const float* __restrict__ z,
                                                     const float* __restrict__ emb,
                                                     const float* __restrict__ counts,
                                                     float* __restrict__ outbuf) {
    __shared__ float E[64 * 65];
    __shared__ int idxs[64];
    __shared__ float lsh[4];
    int blk = blockIdx.x;
    int ct = blk & 15;
    int hwt = (blk >> 4) & 15;
    int b = blk >> 8;
    int c0 = ct * 64;
    int n0 = b * 1024 + hwt * 64;
    int tid = threadIdx.x;
    if (tid < 64) idxs[tid] = (int)outbuf[ZQ_ELEMS + 2 + n0 + tid];
    __syncthreads();
    {
        int i0 = tid >> 4;
        int cc4 = (tid & 15) * 4;
#pragma unroll
        for (int rep = 0; rep < 4; ++rep) {
            int i = i0 + rep * 16;
            float4 v = *(const float4*)(emb + (size_t)idxs[i] * DDIM + c0 + cc4);
            E[i * 65 + cc4 + 0] = v.x;
            E[i * 65 + cc4 + 1] = v.y;
            E[i * 65 + cc4 + 2] = v.z;
            E[i * 65 + cc4 + 3] = v.w;
        }
    }
    __syncthreads();
    float ls = 0.f;
    int hwl = tid & 63;
    int cb = tid >> 6;
    size_t obase = (size_t)b * 1048576 + (size_t)hwt * 64 + hwl;
#pragma unroll
    for (int rep = 0; rep < 16; ++rep) {
        int cc = cb + rep * 4;
        size_t off = obase + (size_t)(c0 + cc) * 1024;
        float zv = z[off];
        float e = E[hwl * 65 + cc];
        float d = e - zv;
        outbuf[off] = zv + d;
        ls += d * d;
    }
#pragma unroll
    for (int off = 32; off; off >>= 1) ls += __shfl_down(ls, off, 64);
    if ((tid & 63) == 0) lsh[tid >> 6] = ls;
    __syncthreads();
    if (tid == 0) {
        float bsum = lsh[0] + lsh[1] + lsh[2] + lsh[3];
        atomicAdd(&outbuf[ZQ_ELEMS], bsum * (1.25f / 8388608.0f));
    }
    if (counts && blk == 0) {
        __shared__ double psh[4];
        double h = 0.0;
        for (int i = tid; i < KCODES; i += 256) {
            float c = counts[i];
            float p = c * (1.0f / 8192.0f);
            h += (double)(p * logf(p + 1e-10f));
        }
#pragma unroll
        for (int off = 32; off; off >>= 1) h += __shfl_down(h, off, 64);
        if ((tid & 63) == 0) psh[tid >> 6] = h;
        __syncthreads();
        if (tid == 0)
            outbuf[ZQ_ELEMS + 1] = (float)exp(-(psh[0] + psh[1] + psh[2] + psh[3]));
    }
}

// ===================== FALLBACK (round-2, fp32 full) =====================
#define SC_PMIN   0
#define SC_PIDX   65536
#define SC_ENORM  131072
#define SC_COUNTS 139264
#define SC_ZNORM  147456

__global__ __launch_bounds__(256) void enorm_kernel(const float* __restrict__ emb,
                                                    float* __restrict__ outbuf) {
    int wave = threadIdx.x >> 6;
    int lane = threadIdx.x & 63;
    int k = blockIdx.x * 4 + wave;
    const float4* row = (const float4*)(emb + (size_t)k * DDIM);
    float s = 0.f;
#pragma unroll
    for (int j = 0; j < 4; ++j) {
        float4 v = row[lane + 64 * j];
        s += v.x * v.x + v.y * v.y + v.z * v.z + v.w * v.w;
    }
#pragma unroll
    for (int off = 32; off; off >>= 1) s += __shfl_down(s, off, 64);
    if (lane == 0) outbuf[SC_ENORM + k] = s;
}

#define BD 32
#define LDT 68
__global__ __launch_bounds__(256) void argmin_kernel(const float* __restrict__ z,
                                                     const float* __restrict__ emb,
                                                     float* __restrict__ outbuf) {
    __shared__ float Asf[BD * LDT];
    __shared__ float Bsf[BD * LDT];
    __shared__ float redV[64 * 17];
    __shared__ float redI[64 * 17];
    int tid = threadIdx.x;
    int tx = tid & 15, ty = tid >> 4;
    int n0 = blockIdx.x * 64;
    int b = n0 >> 10, hw0 = n0 & 1023;
    const float* zbase = z + (size_t)b * 1048576 + hw0;
    int kChunk0 = blockIdx.y * 1024;
    float Zn[4];
#pragma unroll
    for (int i = 0; i < 4; ++i) Zn[i] = outbuf[SC_ZNORM + n0 + 4 * tx + i];
    float bestV[4] = {INFINITY, INFINITY, INFINITY, INFINITY};
    int bestI[4] = {0, 0, 0, 0};
    for (int kt = 0; kt < 16; ++kt) {
        int k0 = kChunk0 + kt * 64;
        double acc64[4][4] = {};
        for (int d0 = 0; d0 < DDIM; d0 += BD) {
            {
                int r4 = (tid & 15) * 4, ddA = tid >> 4;
#pragma unroll
                for (int rep = 0; rep < 2; ++rep) {
                    int dd = ddA + rep * 16;
                    float4 v = *(const float4*)(zbase + (size_t)(d0 + dd) * 1024 + r4);
                    *(float4*)(&Asf[dd * LDT + r4]) = v;
                }
            }
            {
                int dd4 = (tid & 7) * 4, kkB = tid >> 3;
#pragma unroll
                for (int rep = 0; rep < 2; ++rep) {
                    int kk = kkB + rep * 32;
                    float4 v = *(const float4*)(emb + (size_t)(k0 + kk) * DDIM + d0 + dd4);
                    Bsf[(dd4 + 0) * LDT + kk] = v.x;
                    Bsf[(dd4 + 1) * LDT + kk] = v.y;
                    Bsf[(dd4 + 2) * LDT + kk] = v.z;
                    Bsf[(dd4 + 3) * LDT + kk] = v.w;
                }
            }
            __syncthreads();
            float acc[4][4] = {};
#pragma unroll
            for (int dd = 0; dd < BD; ++dd) {
                float4 a = *(const float4*)(&Asf[dd * LDT + 4 * tx]);
                float4 bv = *(const float4*)(&Bsf[dd * LDT + 4 * ty]);
                float ar[4] = {a.x, a.y, a.z, a.w};
                float br[4] = {bv.x, bv.y, bv.z, bv.w};
#pragma unroll
                for (int i = 0; i < 4; ++i)
#pragma unroll
                    for (int j = 0; j < 4; ++j) acc[i][j] += ar[i] * br[j];
            }
            __syncthreads();
#pragma unroll
            for (int i = 0; i < 4; ++i)
#pragma unroll
                for (int j = 0; j < 4; ++j) acc64[i][j] += (double)acc[i][j];
        }
#pragma unroll
        for (int j = 0; j < 4; ++j) {
            int k = k0 + 4 * ty + j;
            float en = outbuf[SC_ENORM + k];
#pragma unroll
            for (int i = 0; i < 4; ++i) {
                float dotf = (float)acc64[i][j];
                float tt = Zn[i] + en;
                float s = tt - 2.0f * dotf;
                if (s < bestV[i]) { bestV[i] = s; bestI[i] = k; }
            }
        }
    }
#pragma unroll
    for (int i = 0; i < 4; ++i) {
        redV[(4 * tx + i) * 17 + ty] = bestV[i];
        redI[(4 * tx + i) * 17 + ty] = (float)bestI[i];
    }
    __syncthreads();
    if (tid < 64) {
        float bv = INFINITY;
        int bi = 0x7fffffff;
        for (int tt = 0; tt < 16; ++tt) {
            float v = redV[tid * 17 + tt];
            int ix = (int)redI[tid * 17 + tt];
            if (v < bv || (v == bv && ix < bi)) { bv = v; bi = ix; }
        }
        int n = n0 + tid;
        outbuf[SC_PMIN + n * 8 + blockIdx.y] = bv;
        outbuf[SC_PIDX + n * 8 + blockIdx.y] = (float)bi;
    }
}

__global__ __launch_bounds__(256) void reduce_kernel(float* __restrict__ outbuf) {
    int n = blockIdx.x * 256 + threadIdx.x;
    float bv = INFINITY;
    int bi = 0x7fffffff;
#pragma unroll
    for (int c = 0; c < 8; ++c) {
        float v = outbuf[SC_PMIN + n * 8 + c];
        int ix = (int)outbuf[SC_PIDX + n * 8 + c];
        if (v < bv || (v == bv && ix < bi)) { bv = v; bi = ix; }
    }
    outbuf[ZQ_ELEMS + 2 + n] = (float)bi;
    atomicAdd(&outbuf[SC_COUNTS + bi], 1.0f);
}

// ===================== launch =====================
extern "C" void kernel_launch(void* const* d_in, const int* in_sizes, int n_in,
                              void* d_out, int out_size, void* d_ws, size_t ws_size,
                              hipStream_t stream) {
    const float* z = (const float*)d_in[0];
    const float* emb = (const float*)d_in[1];
    float* out = (float*)d_out;
    unsigned char* ws = (unsigned char*)d_ws;
    (void)in_sizes; (void)n_in; (void)out_size;

    if (ws_size >= (size_t)W0_NEED) {
        // -------- T0: i8 in ws, zT fills the z_q region of d_out --------
        char* qz8 = (char*)(ws + W0_QZ8);
        char* qe8 = (char*)(ws + W0_QE8);
        float* sz = (float*)(ws + W0_SZ);
        float* se = (float*)(ws + W0_SE);
        unsigned short* cand = (unsigned short*)(ws + W0_CAND);
        float* cval = (float*)(ws + W0_CVAL);
        unsigned int* ccnt = (unsigned int*)(ws + W0_CCNT);
        float* counts = (float*)(ws + W0_COUNTS);
        float* zn = (float*)(ws + W0_ZNORM);
        int* rowming = (int*)(ws + W0_ROWMIN);
        float* zT = out;   // consumed by stage2; gather overwrites afterwards

        prep_kernel<<<4608, 256, 0, stream>>>(z, emb, qz8, qe8, sz, se, zT, zn, ccnt, counts, rowming, out);
        stage1_kernel<<<dim3(64, 64), 256, 0, stream>>>(qz8, qe8, sz, se, cand, cval, ccnt, rowming);
        stage2_kernel<<<2048, 256, 0, stream>>>(z, zT, emb, cand, cval, ccnt, zn, counts, out);
        gather_kernel<<<2048, 256, 0, stream>>>(z, emb, counts, out);
    } else if (ws_size >= (size_t)W1_NEED) {
        // -------- T1: i8 buffers in d_out, no zT --------
        char* qz8 = (char*)out;
        char* qe8 = (char*)out + 8388608;
        float* sz = out + 4194304;
        float* se = out + 4202496;
        unsigned short* cand = (unsigned short*)(ws + W1_CAND);
        float* cval = (float*)(ws + W1_CVAL);
        unsigned int* ccnt = (unsigned int*)(ws + W1_CCNT);
        float* counts = (float*)(ws + W1_COUNTS);
        float* zn = (float*)(ws + W1_ZNORM);
        int* rowming = (int*)(ws + W1_ROWMIN);

        prep_kernel<<<4608, 256, 0, stream>>>(z, emb, qz8, qe8, sz, se, (float*)nullptr, zn, ccnt, counts, rowming, out);
        stage1_kernel<<<dim3(64, 64), 256, 0, stream>>>(qz8, qe8, sz, se, cand, cval, ccnt, rowming);
        stage2_kernel<<<2048, 256, 0, stream>>>(z, (const float*)nullptr, emb, cand, cval, ccnt, zn, counts, out);
        gather_kernel<<<2048, 256, 0, stream>>>(z, emb, counts, out);
    } else if (ws_size >= (size_t)W3_NEED) {
        // -------- T3: i8, cand only (no cval) --------
        char* qz8 = (char*)out;
        char* qe8 = (char*)out + 8388608;
        float* sz = out + 4194304;
        float* se = out + 4202496;
        unsigned short* cand = (unsigned short*)(ws + W3_CAND);
        unsigned int* ccnt = (unsigned int*)(ws + W3_CCNT);
        float* counts = (float*)(ws + W3_COUNTS);
        float* zn = (float*)(ws + W3_ZNORM);
        int* rowming = (int*)(ws + W3_ROWMIN);

        prep_kernel<<<4608, 256, 0, stream>>>(z, emb, qz8, qe8, sz, se, (float*)nullptr, zn, ccnt, counts, rowming, out);
        stage1_kernel<<<dim3(64, 64), 256, 0, stream>>>(qz8, qe8, sz, se, cand, (float*)nullptr, ccnt, rowming);
        stage2_kernel<<<2048, 256, 0, stream>>>(z, (const float*)nullptr, emb, cand,
                                                (const float*)nullptr, ccnt, zn, counts, out);
        gather_kernel<<<2048, 256, 0, stream>>>(z, emb, counts, out);
    } else {
        // -------- fallback: round-2 fp32 path --------
        hipMemsetAsync(out + SC_COUNTS, 0, KCODES * sizeof(float), stream);
        hipMemsetAsync(out + ZQ_ELEMS, 0, sizeof(float), stream);
        enorm_kernel<<<2048, 256, 0, stream>>>(emb, out);
        znorm_kernel<<<32, 256, 0, stream>>>(z, out + SC_ZNORM);
        argmin_kernel<<<dim3(128, 8), 256, 0, stream>>>(z, emb, out);
        reduce_kernel<<<32, 256, 0, stream>>>(out);
        perp_kernel<<<1, 1024, 0, stream>>>(out + SC_COUNTS, out);
        gather_kernel<<<2048, 256, 0, stream>>>(z, emb, (const float*)nullptr, out);
    }
}

// Round 11
// 260.949 us; speedup vs baseline: 1.0890x; 1.0890x over previous
//
#include <hip/hip_runtime.h>
#include <math.h>

// Problem constants
#define NROWS 8192
#define KCODES 8192
#define DDIM 1024
#define ZQ_ELEMS 8388608  // 8*1024*32*32

typedef int i4 __attribute__((ext_vector_type(4)));   // i8 MFMA operands / i32 acc

// ===================== T0 ws layout (i8 + candidates; zT lives in d_out) =====================
#define W0_QZ8     0u
#define W0_QE8     8388608u
#define W0_SZ      16777216u
#define W0_SE      16809984u
#define W0_CAND    16842752u   // u16 8192*128
#define W0_CVAL    18939904u   // f32 8192*128
#define W0_CCNT    23134208u
#define W0_COUNTS  23166976u
#define W0_ZNORM   23199744u
#define W0_ROWMIN  23232512u
#define W0_NEED    23265280u
// ===================== T1 ws layout (i8 buffers in d_out) =====================
#define W1_CAND    0u
#define W1_CVAL    2097152u
#define W1_CCNT    6291456u
#define W1_COUNTS  6324224u
#define W1_ZNORM   6356992u
#define W1_ROWMIN  6389760u
#define W1_NEED    6422528u
// ===================== T3 ws layout =====================
#define W3_CAND    0u
#define W3_CCNT    2097152u
#define W3_COUNTS  2129920u
#define W3_ZNORM   2162688u
#define W3_ROWMIN  2195456u
#define W3_NEED    2228224u

#define CAP 128
#define MARGIN  7.5e-4f  // stage1 collection margin (>=9 sigma of i8 s1 error + bucket)
#define MARGIN2 6e-4f    // stage2 filter margin (~8.7 sigma + bucket)

typedef __attribute__((address_space(3))) unsigned int lds_u32;
typedef __attribute__((address_space(1))) const unsigned int glb_u32;
static __device__ __forceinline__ void glds16(const void* g, void* l) {
    __builtin_amdgcn_global_load_lds((glb_u32*)g, (lds_u32*)l, 16, 0, 0);
}

// ---------------- fused prep: z single-pass (norm+max+zT+quantize from regs) + e quant ----------------
// blocks [0,512): z strip (b, 16 hw); blocks [512,4608): 2 emb rows each.
// z part: 64d x 16hw dbuf transpose tile, values held in 16 float4 regs;
// norm/max via 16-lane butterfly (all lanes get result -> no LDS broadcast);
// quantize straight from registers -> NO second pass at all. (R10: kept, ~-5us)
__global__ __launch_bounds__(256) void prep_kernel(const float* __restrict__ z,
                                                   const float* __restrict__ emb,
                                                   char* __restrict__ qz8,
                                                   char* __restrict__ qe8,
                                                   float* __restrict__ sz,
                                                   float* __restrict__ se,
                                                   float* __restrict__ zT,
                                                   float* __restrict__ zn,
                                                   unsigned int* __restrict__ ccnt,
                                                   float* __restrict__ counts,
                                                   int* __restrict__ rowming,
                                                   float* __restrict__ outbuf) {
    int blk = blockIdx.x;
    int t = threadIdx.x;
    if (blk >= 512) {
        // ---- emb rows: per-row max -> scale -> int8 ----
        __shared__ float wm[4];
        int k0 = (blk - 512) * 2;
        int half = t >> 7;
        int li = t & 127;
        int row = k0 + half;
        const float* er = emb + (size_t)row * 1024 + li * 8;
        float4 v0 = *(const float4*)er;
        float4 v1 = *(const float4*)(er + 4);
        float lm = fmaxf(fmaxf(fmaxf(fabsf(v0.x), fabsf(v0.y)), fmaxf(fabsf(v0.z), fabsf(v0.w))),
                         fmaxf(fmaxf(fabsf(v1.x), fabsf(v1.y)), fmaxf(fabsf(v1.z), fabsf(v1.w))));
#pragma unroll
        for (int off = 32; off; off >>= 1) lm = fmaxf(lm, __shfl_down(lm, off, 64));
        int w = t >> 6;
        if ((t & 63) == 0) wm[w] = lm;
        __syncthreads();
        float rmax = fmaxf(wm[half * 2], wm[half * 2 + 1]);
        float inv = rmax > 0.f ? 127.f / rmax : 0.f;
        int q0 = (int)rintf(v0.x * inv), q1 = (int)rintf(v0.y * inv);
        int q2 = (int)rintf(v0.z * inv), q3 = (int)rintf(v0.w * inv);
        int q4 = (int)rintf(v1.x * inv), q5 = (int)rintf(v1.y * inv);
        int q6 = (int)rintf(v1.z * inv), q7 = (int)rintf(v1.w * inv);
        uint2 o;
        o.x = (q0 & 255) | ((q1 & 255) << 8) | ((q2 & 255) << 16) | ((unsigned)(q3 & 255) << 24);
        o.y = (q4 & 255) | ((q5 & 255) << 8) | ((q6 & 255) << 16) | ((unsigned)(q7 & 255) << 24);
        *(uint2*)(qe8 + (size_t)row * 1024 + li * 8) = o;
        if (li == 0) se[row] = rmax * (1.f / 127.f);
        return;
    }
    // init slices (blocks 0..255 cover 8192)
    if (blk < 256 && t < 32) {
        int i = blk * 32 + t;
        ccnt[i] = 0u;
        counts[i] = 0.f;
        rowming[i] = 0x7f7f7f7f;
    }
    if (blk == 0 && t == 32) outbuf[ZQ_ELEMS] = 0.f;

    __shared__ float T[2][64 * 17];
    int b = blk >> 6;
    int hw0 = (blk & 63) * 16;
    int dsub = t >> 2, hseg = (t & 3) * 4;   // load role: 64 d x 16 hw
    int hsub = t >> 4, ddg = (t & 15) * 4;   // emit role: 16 hw x 16 d-groups
    double acc = 0.0;
    float lmax = 0.f;
    float4 tv[16];
    int p = 0;
#pragma unroll
    for (int dt = 0; dt < 16; ++dt) {
        int d0 = dt * 64;
        float4 v = *(const float4*)(z + (size_t)b * 1048576 + (size_t)(d0 + dsub) * 1024 + hw0 + hseg);
        float* Tp = T[p];
        Tp[dsub * 17 + hseg + 0] = v.x;
        Tp[dsub * 17 + hseg + 1] = v.y;
        Tp[dsub * 17 + hseg + 2] = v.z;
        Tp[dsub * 17 + hseg + 3] = v.w;
        __syncthreads();
        float t0 = Tp[(ddg + 0) * 17 + hsub];
        float t1 = Tp[(ddg + 1) * 17 + hsub];
        float t2 = Tp[(ddg + 2) * 17 + hsub];
        float t3 = Tp[(ddg + 3) * 17 + hsub];
        tv[dt].x = t0; tv[dt].y = t1; tv[dt].z = t2; tv[dt].w = t3;
        if (zT) {
            float4 o4; o4.x = t0; o4.y = t1; o4.z = t2; o4.w = t3;
            *(float4*)(zT + ((size_t)(b * 1024 + hw0 + hsub) << 10) + d0 + ddg) = o4;
        }
        acc += (double)t0 * t0 + (double)t1 * t1 + (double)t2 * t2 + (double)t3 * t3;
        lmax = fmaxf(lmax, fmaxf(fmaxf(fabsf(t0), fabsf(t1)), fmaxf(fabsf(t2), fabsf(t3))));
        p ^= 1;
    }
#pragma unroll
    for (int m = 8; m; m >>= 1) {
        acc += __shfl_xor(acc, m, 16);
        lmax = fmaxf(lmax, __shfl_xor(lmax, m, 16));
    }
    if ((t & 15) == 0) {
        zn[b * 1024 + hw0 + hsub] = (float)acc;
        sz[b * 1024 + hw0 + hsub] = lmax * (1.f / 127.f);
    }
    // quantize straight from registers (same inv bits as the 2-pass version)
    float inv = lmax > 0.f ? 127.f / lmax : 0.f;
    int* qo = (int*)(qz8 + ((size_t)(b * 1024 + hw0 + hsub) << 10) + ddg);
#pragma unroll
    for (int dt = 0; dt < 16; ++dt) {
        int q0 = (int)rintf(tv[dt].x * inv), q1 = (int)rintf(tv[dt].y * inv);
        int q2 = (int)rintf(tv[dt].z * inv), q3 = (int)rintf(tv[dt].w * inv);
        qo[dt * 16] = (q0 & 255) | ((q1 & 255) << 8) | ((q2 & 255) << 16) | ((unsigned)(q3 & 255) << 24);
    }
}

// ---------------- |z_n|^2 standalone (fp32 fallback path only) ----------------
__global__ __launch_bounds__(256) void znorm_kernel(const float* __restrict__ z,
                                                    float* __restrict__ zn) {
    int b = blockIdx.x >> 2;
    int hw = (blockIdx.x & 3) * 256 + threadIdx.x;
    const float* base = z + (size_t)b * 1048576 + hw;
    double s = 0.0;
#pragma unroll 16
    for (int d = 0; d < DDIM; ++d) {
        float v = base[(size_t)d * 1024];
        s += (double)v * (double)v;
    }
    zn[b * 1024 + hw] = (float)s;
}

// ---------------- stage 1: i8 MFMA GEMM + candidate collect ----------------
// grid (64 x 64), 256 thr (4 waves 2x2), tile 128x128, BK=128 i8, 8 segments.
// CONFIRMED LOCAL OPTIMUM (105-106us). REGRESSED variants: R2 256^2-ring 155,
// R3 BK=64-dbuf 121, R4 depth-2-vmcnt 145, R6 A-direct 199, R8 XCD-remap 115
// (FETCH 43->232MB), R10 fire-and-forget prefix-min 113 (staleness loosened
// thresholds -> more candidate-collection atomics; WRITE dropped 38->11MB but
// time rose). Keep: dual glds16, linear dispatch, atomicMin-WITH-return.
__global__ __launch_bounds__(256, 4) void stage1_kernel(const char* __restrict__ qz,
                                                        const char* __restrict__ qe,
                                                        const float* __restrict__ sz,
                                                        const float* __restrict__ se,
                                                        unsigned short* __restrict__ cand,
                                                        float* __restrict__ cval,
                                                        unsigned int* __restrict__ ccnt,
                                                        int* __restrict__ rowming) {
    __shared__ char As[128 * 128];   // [row][8 chunks of 16 i8], chunk ^= row&7
    __shared__ char Bs[128 * 128];
    __shared__ int rowminS[128];
    __shared__ float szS[128], seS[128];

    int t = threadIdx.x;
    int w = t >> 6, lane = t & 63;
    int q = lane >> 4, l15 = lane & 15;
    int wr = (w >> 1) * 64, wc = (w & 1) * 64;
    int n0 = blockIdx.x * 128;
    int k0 = blockIdx.y * 128;
    if (t < 128) {
        rowminS[t] = 0x7f7f7f7f;
        szS[t] = sz[n0 + t];
        seS[t] = se[k0 + t];
    }

    const char* gA[4];
    const char* gB[4];
    {
        int rsub = lane >> 3;
        int clog = (lane & 7) ^ (rsub & 7);
#pragma unroll
        for (int c = 0; c < 4; ++c) {
            int cc = w * 4 + c;
            int r = cc * 8 + rsub;
            gA[c] = qz + ((size_t)(n0 + r) << 10) + clog * 16;
            gB[c] = qe + ((size_t)(k0 + r) << 10) + clog * 16;
        }
    }
    int Aoff[4][2], Boff[4][2];
#pragma unroll
    for (int rf = 0; rf < 4; ++rf) {
#pragma unroll
        for (int ks = 0; ks < 2; ++ks) {
            int r = wr + rf * 16 + l15;
            Aoff[rf][ks] = r * 128 + (((ks * 4 + q) ^ (r & 7)) * 16);
            int rb = wc + rf * 16 + l15;
            Boff[rf][ks] = rb * 128 + (((ks * 4 + q) ^ (rb & 7)) * 16);
        }
    }

    i4 acc[4][4];
    const i4 z4 = {0, 0, 0, 0};
#pragma unroll
    for (int rf = 0; rf < 4; ++rf)
#pragma unroll
        for (int cf = 0; cf < 4; ++cf) acc[rf][cf] = z4;

    for (int s = 0; s < 8; ++s) {
        __syncthreads();
#pragma unroll
        for (int c = 0; c < 4; ++c) {
            int cc = w * 4 + c;
            glds16(gA[c], As + cc * 1024);
            glds16(gB[c], Bs + cc * 1024);
            gA[c] += 128;
            gB[c] += 128;
        }
        __syncthreads();
#pragma unroll
        for (int ks = 0; ks < 2; ++ks) {
            i4 af[4], bf[4];
#pragma unroll
            for (int rf = 0; rf < 4; ++rf) af[rf] = *(const i4*)(As + Aoff[rf][ks]);
#pragma unroll
            for (int cf = 0; cf < 4; ++cf) bf[cf] = *(const i4*)(Bs + Boff[cf][ks]);
#pragma unroll
            for (int rf = 0; rf < 4; ++rf)
#pragma unroll
                for (int cf = 0; cf < 4; ++cf)
                    acc[rf][cf] = __builtin_amdgcn_mfma_i32_16x16x64_i8(af[rf], bf[cf], acc[rf][cf], 0, 0, 0);
        }
    }

    // ---- epilogue: s1 = 16 - 2*idot*sz*se (positive -> int-ordered min) ----
#pragma unroll
    for (int rf = 0; rf < 4; ++rf) {
#pragma unroll
        for (int reg = 0; reg < 4; ++reg) {
            int r = wr + rf * 16 + q * 4 + reg;
            float zs = szS[r];
            float m4 = INFINITY;
#pragma unroll
            for (int cf = 0; cf < 4; ++cf) {
                float s1 = 16.0f - 2.0f * (float)acc[rf][cf][reg] * (zs * seS[wc + cf * 16 + l15]);
                m4 = fminf(m4, s1);
            }
            m4 = fminf(m4, __shfl_xor(m4, 1, 16));
            m4 = fminf(m4, __shfl_xor(m4, 2, 16));
            m4 = fminf(m4, __shfl_xor(m4, 4, 16));
            m4 = fminf(m4, __shfl_xor(m4, 8, 16));
            if (l15 == 0) atomicMin(&rowminS[r], __float_as_int(m4));
        }
    }
    __syncthreads();
    if (t < 128) {
        int mine = rowminS[t];
        int gold = atomicMin(&rowming[n0 + t], mine);   // device-scope prefix-min share
        rowminS[t] = gold < mine ? gold : mine;
    }
    __syncthreads();
#pragma unroll
    for (int rf = 0; rf < 4; ++rf) {
#pragma unroll
        for (int reg = 0; reg < 4; ++reg) {
            int r = wr + rf * 16 + q * 4 + reg;
            float zs = szS[r];
            float rm = __int_as_float(rowminS[r]) + MARGIN;
#pragma unroll
            for (int cf = 0; cf < 4; ++cf) {
                float s1 = 16.0f - 2.0f * (float)acc[rf][cf][reg] * (zs * seS[wc + cf * 16 + l15]);
                if (s1 <= rm) {
                    int kg = k0 + wc + cf * 16 + l15;
                    unsigned pos = atomicAdd(&ccnt[n0 + r], 1u);
                    if (pos < CAP) {
                        cand[(size_t)(n0 + r) * CAP + pos] = (unsigned short)kg;
                        if (cval) cval[(size_t)(n0 + r) * CAP + pos] = s1;
                    }
                }
            }
        }
    }
}

// ---------------- stage 2: 1 wave per row; ballot fast-exit, else exact rescore ----------------
__global__ __launch_bounds__(256) void stage2_kernel(const float* __restrict__ z,
                                                     const float* __restrict__ zT,
                                                     const float* __restrict__ emb,
                                                     const unsigned short* __restrict__ cand,
                                                     const float* __restrict__ cval,
                                                     const unsigned int* __restrict__ ccnt,
                                                     const float* __restrict__ zn,
                                                     float* __restrict__ counts,
                                                     float* __restrict__ outbuf) {
    int t = threadIdx.x;
    int w = t >> 6, lane = t & 63;
    int n = blockIdx.x * 4 + w;
    unsigned cnt = ccnt[n];
    float Zn = zn[n];
    float thr = INFINITY;

    if (cval && cnt <= CAP) {
        const float* cv = cval + (size_t)n * CAP;
        float v0 = (unsigned)lane < cnt ? cv[lane] : INFINITY;
        float v1 = (unsigned)(64 + lane) < cnt ? cv[64 + lane] : INFINITY;
        float m = fminf(v0, v1);
#pragma unroll
        for (int off = 32; off; off >>= 1) m = fminf(m, __shfl_xor(m, off, 64));
        thr = m + MARGIN2;
        unsigned long long m0 = __ballot(v0 <= thr);
        unsigned long long m1 = __ballot(v1 <= thr);
        if (__popcll(m0) + __popcll(m1) == 1) {
            if (lane == 0) {
                int slot = m0 ? ((int)__ffsll((unsigned long long)m0) - 1)
                              : 64 + ((int)__ffsll((unsigned long long)m1) - 1);
                int K = cand[(size_t)n * CAP + slot];
                outbuf[ZQ_ELEMS + 2 + n] = (float)K;
                atomicAdd(&counts[K], 1.0f);
            }
            return;
        }
    }
    // ambiguous (or no cval / overflow): z row -> registers, exact rescore
    float4 zreg[4];
    if (zT) {
        const float4* zr = (const float4*)(zT + ((size_t)n << 10));
#pragma unroll
        for (int i = 0; i < 4; ++i) zreg[i] = zr[lane + i * 64];
    } else {
        int b = n >> 10, hw = n & 1023;
        const float* zb = z + (size_t)b * 1048576 + hw;
#pragma unroll
        for (int i = 0; i < 4; ++i) {
            int e = (lane + i * 64) * 4;
            zreg[i].x = zb[(size_t)(e + 0) << 10];
            zreg[i].y = zb[(size_t)(e + 1) << 10];
            zreg[i].z = zb[(size_t)(e + 2) << 10];
            zreg[i].w = zb[(size_t)(e + 3) << 10];
        }
    }
    float bs = INFINITY;
    int bk = 0x7fffffff;
    if (cnt <= CAP) {
        for (unsigned c = 0; c < cnt; ++c) {
            if (cval && cval[(size_t)n * CAP + c] > thr) continue;
            int k = cand[(size_t)n * CAP + c];
            const float4* e4 = (const float4*)(emb + (size_t)k * 1024);
            double pd = 0.0;
#pragma unroll
            for (int i = 0; i < 4; ++i) {
                float4 e = e4[lane + i * 64];
                float4 zv = zreg[i];
                float p = (zv.x * e.x + zv.y * e.y) + (zv.z * e.z + zv.w * e.w);
                pd += (double)p;
            }
#pragma unroll
            for (int off = 32; off; off >>= 1) pd += __shfl_down(pd, off, 64);
            if (lane == 0) {
                float s = Zn - 2.0f * (float)pd;   // fl(Z + |e|^2) == Z (|e|^2 < half-ulp)
                if (s < bs || (s == bs && k < bk)) { bs = s; bk = k; }
            }
        }
    } else {
        for (int k = 0; k < KCODES; ++k) {
            const float4* e4 = (const float4*)(emb + (size_t)k * 1024);
            double pd = 0.0;
#pragma unroll
            for (int i = 0; i < 4; ++i) {
                float4 e = e4[lane + i * 64];
                float4 zv = zreg[i];
                float p = (zv.x * e.x + zv.y * e.y) + (zv.z * e.z + zv.w * e.w);
                pd += (double)p;
            }
#pragma unroll
            for (int off = 32; off; off >>= 1) pd += __shfl_down(pd, off, 64);
            if (lane == 0) {
                float s = Zn - 2.0f * (float)pd;
                if (s < bs || (s == bs && k < bk)) { bs = s; bk = k; }
            }
        }
    }
    if (lane == 0) {
        outbuf[ZQ_ELEMS + 2 + n] = (float)bk;
        atomicAdd(&counts[bk], 1.0f);
    }
}

// ---------------- perplexity standalone (fallback path only) ----------------
__global__ __launch_bounds__(1024) void perp_kernel(const float* __restrict__ counts,
                                                    float* __restrict__ outbuf) {
    __shared__ double sh[16];
    int tid = threadIdx.x;
    double h = 0.0;
    for (int i = tid; i < KCODES; i += 1024) {
        float c = counts[i];
        float p = c * (1.0f / 8192.0f);
        h += (double)(p * logf(p + 1e-10f));
    }
#pragma unroll
    for (int off = 32; off; off >>= 1) h += __shfl_down(h, off, 64);
    if ((tid & 63) == 0) sh[tid >> 6] = h;
    __syncthreads();
    if (tid == 0) {
        double H = 0.0;
#pragma unroll
        for (int i = 0; i < 16; ++i) H += sh[i];
        outbuf[ZQ_ELEMS + 1] = (float)exp(-H);
    }
}

// ---------------- gather + transpose + STE + loss (+ fused perplexity in block 0) ----------------
__global__ __launch_bounds__(256) void gather_kernel(const float* __restrict__ z,
                                                     const float* __restrict__ emb,
                                                     const float* __restrict__ counts,
                                                     float* __restrict__ outbuf) {
    __shared__ float E[64 * 65];
    __shared__ int idxs[64];
    __shared__ float lsh[4];
    int blk = blockIdx.x;
    int ct = blk & 15;
    int hwt = (blk >> 4) & 15;
    int b = blk >> 8;
    int c0 = ct * 64;
    int n0 = b * 1024 + hwt * 64;
    int tid = threadIdx.x;
    if (tid < 64) idxs[tid] = (int)outbuf[ZQ_ELEMS + 2 + n0 + tid];
    __syncthreads();
    {
        int i0 = tid >> 4;
        int cc4 = (tid & 15) * 4;
#pragma unroll
        for (int rep = 0; rep < 4; ++rep) {
            int i = i0 + rep * 16;
            float4 v = *(const float4*)(emb + (size_t)idxs[i] * DDIM + c0 + cc4);
            E[i * 65 + cc4 + 0] = v.x;
            E[i * 65 + cc4 + 1] = v.y;
            E[i * 65 + cc4 + 2] = v.z;
            E[i * 65 + cc4 + 3] = v.w;
        }
    }
    __syncthreads();
    float ls = 0.f;
    int hwl = tid & 63;
    int cb = tid >> 6;
    size_t obase = (size_t)b * 1048576 + (size_t)hwt * 64 + hwl;
#pragma unroll
    for (int rep = 0; rep < 16; ++rep) {
        int cc = cb + rep * 4;
        size_t off = obase + (size_t)(c0 + cc) * 1024;
        float zv = z[off];
        float e = E[hwl * 65 + cc];
        float d = e - zv;
        outbuf[off] = zv + d;
        ls += d * d;
    }
#pragma unroll
    for (int off = 32; off; off >>= 1) ls += __shfl_down(ls, off, 64);
    if ((tid & 63) == 0) lsh[tid >> 6] = ls;
    __syncthreads();
    if (tid == 0) {
        float bsum = lsh[0] + lsh[1] + lsh[2] + lsh[3];
        atomicAdd(&outbuf[ZQ_ELEMS], bsum * (1.25f / 8388608.0f));
    }
    if (counts && blk == 0) {
        __shared__ double psh[4];
        double h = 0.0;
        for (int i = tid; i < KCODES; i += 256) {
            float c = counts[i];
            float p = c * (1.0f / 8192.0f);
            h += (double)(p * logf(p + 1e-10f));
        }
#pragma unroll
        for (int off = 32; off; off >>= 1) h += __shfl_down(h, off, 64);
        if ((tid & 63) == 0) psh[tid >> 6] = h;
        __syncthreads();
        if (tid == 0)
            outbuf[ZQ_ELEMS + 1] = (float)exp(-(psh[0] + psh[1] + psh[2] + psh[3]));
    }
}

// ===================== FALLBACK (round-2, fp32 full) =====================
#define SC_PMIN   0
#define SC_PIDX   65536
#define SC_ENORM  131072
#define SC_COUNTS 139264
#define SC_ZNORM  147456

__global__ __launch_bounds__(256) void enorm_kernel(const float* __restrict__ emb,
                                                    float* __restrict__ outbuf) {
    int wave = threadIdx.x >> 6;
    int lane = threadIdx.x & 63;
    int k = blockIdx.x * 4 + wave;
    const float4* row = (const float4*)(emb + (size_t)k * DDIM);
    float s = 0.f;
#pragma unroll
    for (int j = 0; j < 4; ++j) {
        float4 v = row[lane + 64 * j];
        s += v.x * v.x + v.y * v.y + v.z * v.z + v.w * v.w;
    }
#pragma unroll
    for (int off = 32; off; off >>= 1) s += __shfl_down(s, off, 64);
    if (lane == 0) outbuf[SC_ENORM + k] = s;
}

#define BD 32
#define LDT 68
__global__ __launch_bounds__(256) void argmin_kernel(const float* __restrict__ z,
                                                     const float* __restrict__ emb,
                                                     float* __restrict__ outbuf) {
    __shared__ float Asf[BD * LDT];
    __shared__ float Bsf[BD * LDT];
    __shared__ float redV[64 * 17];
    __shared__ float redI[64 * 17];
    int tid = threadIdx.x;
    int tx = tid & 15, ty = tid >> 4;
    int n0 = blockIdx.x * 64;
    int b = n0 >> 10, hw0 = n0 & 1023;
    const float* zbase = z + (size_t)b * 1048576 + hw0;
    int kChunk0 = blockIdx.y * 1024;
    float Zn[4];
#pragma unroll
    for (int i = 0; i < 4; ++i) Zn[i] = outbuf[SC_ZNORM + n0 + 4 * tx + i];
    float bestV[4] = {INFINITY, INFINITY, INFINITY, INFINITY};
    int bestI[4] = {0, 0, 0, 0};
    for (int kt = 0; kt < 16; ++kt) {
        int k0 = kChunk0 + kt * 64;
        double acc64[4][4] = {};
        for (int d0 = 0; d0 < DDIM; d0 += BD) {
            {
                int r4 = (tid & 15) * 4, ddA = tid >> 4;
#pragma unroll
                for (int rep = 0; rep < 2; ++rep) {
                    int dd = ddA + rep * 16;
                    float4 v = *(const float4*)(zbase + (size_t)(d0 + dd) * 1024 + r4);
                    *(float4*)(&Asf[dd * LDT + r4]) = v;
                }
            }
            {
                int dd4 = (tid & 7) * 4, kkB = tid >> 3;
#pragma unroll
                for (int rep = 0; rep < 2; ++rep) {
                    int kk = kkB + rep * 32;
                    float4 v = *(const float4*)(emb + (size_t)(k0 + kk) * DDIM + d0 + dd4);
                    Bsf[(dd4 + 0) * LDT + kk] = v.x;
                    Bsf[(dd4 + 1) * LDT + kk] = v.y;
                    Bsf[(dd4 + 2) * LDT + kk] = v.z;
                    Bsf[(dd4 + 3) * LDT + kk] = v.w;
                }
            }
            __syncthreads();
            float acc[4][4] = {};
#pragma unroll
            for (int dd = 0; dd < BD; ++dd) {
                float4 a = *(const float4*)(&Asf[dd * LDT + 4 * tx]);
                float4 bv = *(const float4*)(&Bsf[dd * LDT + 4 * ty]);
                float ar[4] = {a.x, a.y, a.z, a.w};
                float br[4] = {bv.x, bv.y, bv.z, bv.w};
#pragma unroll
                for (int i = 0; i < 4; ++i)
#pragma unroll
                    for (int j = 0; j < 4; ++j) acc[i][j] += ar[i] * br[j];
            }
            __syncthreads();
#pragma unroll
            for (int i = 0; i < 4; ++i)
#pragma unroll
                for (int j = 0; j < 4; ++j) acc64[i][j] += (double)acc[i][j];
        }
#pragma unroll
        for (int j = 0; j < 4; ++j) {
            int k = k0 + 4 * ty + j;
            float en = outbuf[SC_ENORM + k];
#pragma unroll
            for (int i = 0; i < 4; ++i) {
                float dotf = (float)acc64[i][j];
                float tt = Zn[i] + en;
                float s = tt - 2.0f * dotf;
                if (s < bestV[i]) { bestV[i] = s; bestI[i] = k; }
            }
        }
    }
#pragma unroll
    for (int i = 0; i < 4; ++i) {
        redV[(4 * tx + i) * 17 + ty] = bestV[i];
        redI[(4 * tx + i) * 17 + ty] = (float)bestI[i];
    }
    __syncthreads();
    if (tid < 64) {
        float bv = INFINITY;
        int bi = 0x7fffffff;
        for (int tt = 0; tt < 16; ++tt) {
            float v = redV[tid * 17 + tt];
            int ix = (int)redI[tid * 17 + tt];
            if (v < bv || (v == bv && ix < bi)) { bv = v; bi = ix; }
        }
        int n = n0 + tid;
        outbuf[SC_PMIN + n * 8 + blockIdx.y] = bv;
        outbuf[SC_PIDX + n * 8 + blockIdx.y] = (float)bi;
    }
}

__global__ __launch_bounds__(256) void reduce_kernel(float* __restrict__ outbuf) {
    int n = blockIdx.x * 256 + threadIdx.x;
    float bv = INFINITY;
    int bi = 0x7fffffff;
#pragma unroll
    for (int c = 0; c < 8; ++c) {
        float v = outbuf[SC_PMIN + n * 8 + c];
        int ix = (int)outbuf[SC_PIDX + n * 8 + c];
        if (v < bv || (v == bv && ix < bi)) { bv = v; bi = ix; }
    }
    outbuf[ZQ_ELEMS + 2 + n] = (float)bi;
    atomicAdd(&outbuf[SC_COUNTS + bi], 1.0f);
}

// ===================== launch =====================
extern "C" void kernel_launch(void* const* d_in, const int* in_sizes, int n_in,
                              void* d_out, int out_size, void* d_ws, size_t ws_size,
                              hipStream_t stream) {
    const float* z = (const float*)d_in[0];
    const float* emb = (const float*)d_in[1];
    float* out = (float*)d_out;
    unsigned char* ws = (unsigned char*)d_ws;
    (void)in_sizes; (void)n_in; (void)out_size;

    if (ws_size >= (size_t)W0_NEED) {
        // -------- T0: i8 in ws, zT fills the z_q region of d_out --------
        char* qz8 = (char*)(ws + W0_QZ8);
        char* qe8 = (char*)(ws + W0_QE8);
        float* sz = (float*)(ws + W0_SZ);
        float* se = (float*)(ws + W0_SE);
        unsigned short* cand = (unsigned short*)(ws + W0_CAND);
        float* cval = (float*)(ws + W0_CVAL);
        unsigned int* ccnt = (unsigned int*)(ws + W0_CCNT);
        float* counts = (float*)(ws + W0_COUNTS);
        float* zn = (float*)(ws + W0_ZNORM);
        int* rowming = (int*)(ws + W0_ROWMIN);
        float* zT = out;   // consumed by stage2; gather overwrites afterwards

        prep_kernel<<<4608, 256, 0, stream>>>(z, emb, qz8, qe8, sz, se, zT, zn, ccnt, counts, rowming, out);
        stage1_kernel<<<dim3(64, 64), 256, 0, stream>>>(qz8, qe8, sz, se, cand, cval, ccnt, rowming);
        stage2_kernel<<<2048, 256, 0, stream>>>(z, zT, emb, cand, cval, ccnt, zn, counts, out);
        gather_kernel<<<2048, 256, 0, stream>>>(z, emb, counts, out);
    } else if (ws_size >= (size_t)W1_NEED) {
        // -------- T1: i8 buffers in d_out, no zT --------
        char* qz8 = (char*)out;
        char* qe8 = (char*)out + 8388608;
        float* sz = out + 4194304;
        float* se = out + 4202496;
        unsigned short* cand = (unsigned short*)(ws + W1_CAND);
        float* cval = (float*)(ws + W1_CVAL);
        unsigned int* ccnt = (unsigned int*)(ws + W1_CCNT);
        float* counts = (float*)(ws + W1_COUNTS);
        float* zn = (float*)(ws + W1_ZNORM);
        int* rowming = (int*)(ws + W1_ROWMIN);

        prep_kernel<<<4608, 256, 0, stream>>>(z, emb, qz8, qe8, sz, se, (float*)nullptr, zn, ccnt, counts, rowming, out);
        stage1_kernel<<<dim3(64, 64), 256, 0, stream>>>(qz8, qe8, sz, se, cand, cval, ccnt, rowming);
        stage2_kernel<<<2048, 256, 0, stream>>>(z, (const float*)nullptr, emb, cand, cval, ccnt, zn, counts, out);
        gather_kernel<<<2048, 256, 0, stream>>>(z, emb, counts, out);
    } else if (ws_size >= (size_t)W3_NEED) {
        // -------- T3: i8, cand only (no cval) --------
        char* qz8 = (char*)out;
        char* qe8 = (char*)out + 8388608;
        float* sz = out + 4194304;
        float* se = out + 4202496;
        unsigned short* cand = (unsigned short*)(ws + W3_CAND);
        unsigned int* ccnt = (unsigned int*)(ws + W3_CCNT);
        float* counts = (float*)(ws + W3_COUNTS);
        float* zn = (float*)(ws + W3_ZNORM);
        int* rowming = (int*)(ws + W3_ROWMIN);

        prep_kernel<<<4608, 256, 0, stream>>>(z, emb, qz8, qe8, sz, se, (float*)nullptr, zn, ccnt, counts, rowming, out);
        stage1_kernel<<<dim3(64, 64), 256, 0, stream>>>(qz8, qe8, sz, se, cand, (float*)nullptr, ccnt, rowming);
        stage2_kernel<<<2048, 256, 0, stream>>>(z, (const float*)nullptr, emb, cand,
                                                (const float*)nullptr, ccnt, zn, counts, out);
        gather_kernel<<<2048, 256, 0, stream>>>(z, emb, counts, out);
    } else {
        // -------- fallback: round-2 fp32 path --------
        hipMemsetAsync(out + SC_COUNTS, 0, KCODES * sizeof(float), stream);
        hipMemsetAsync(out + ZQ_ELEMS, 0, sizeof(float), stream);
        enorm_kernel<<<2048, 256, 0, stream>>>(emb, out);
        znorm_kernel<<<32, 256, 0, stream>>>(z, out + SC_ZNORM);
        argmin_kernel<<<dim3(128, 8), 256, 0, stream>>>(z, emb, out);
        reduce_kernel<<<32, 256, 0, stream>>>(out);
        perp_kernel<<<1, 1024, 0, stream>>>(out + SC_COUNTS, out);
        gather_kernel<<<2048, 256, 0, stream>>>(z, emb, (const float*)nullptr, out);
    }
}